// Round 5
// baseline (703.156 us; speedup 1.0000x reference)
//
#include <hip/hip_runtime.h>
#include <hip/hip_bf16.h>

// QRNN: T=512, B=64, IN=512, H=1024, OUT=512. fp32 in/out.
// R11: GEMM tile 128x512 (was 256x256). Theory: K-step time (3025 cyc/CU)
// is pinned by A-panel delivery from L3 -- per-XCD working set (A-window
// ~2.7MB + B 3MB) > 4MiB L2, so A re-streams from Infinity Cache once per
// N-block column (gx=6 passes x 67MB = 402MB/dispatch ~= 3.3 TB/s = L3
// ceiling). A-restream factor = N/BN; BN 256->512 halves it (200MB).
// Geometry: 8 waves (2M x 4N), per-wave 64x128 (acc[4][8]=128 regs), BK=32,
// 3-slot LDS ring (A 8K + B 32K per slot = 120 KiB), stage kt+2 during kt,
// vmcnt(5) checkpoint (tile kt+2 in flight), same 2x16-MFMA phase split,
// lgkmcnt(0)+sched_barrier+setprio pattern, same proven XOR swizzle
// ((c&3)^((r>>1)&3) on 16B chunks), XCD-chunked bijective remap, M-major.
// MFMA K-order unchanged -> bitwise-same output.
// R10 retained: 4-wide scans, p2-folded-into-p3, fast exp2/rcp activations,
// bf16 g, x_bf aliased into h1, CW=512 chunks, RNE f2bf.

#define QT 512
#define QB 64
#define QIN 512
#define QH 1024
#define QOUT 512
#define QM (QT * QB)
#define SEG 32
#define SL (QT / SEG)  // 16

typedef unsigned short ushort_t;
typedef __attribute__((ext_vector_type(8))) short bf16x8;
typedef __attribute__((ext_vector_type(4))) float f32x4;

__device__ __forceinline__ float blo(unsigned int u) {
    union { unsigned int i; float f; } v;
    v.i = u << 16;
    return v.f;
}

__device__ __forceinline__ float bhi(unsigned int u) {
    union { unsigned int i; float f; } v;
    v.i = u & 0xffff0000u;
    return v.f;
}

__device__ __forceinline__ ushort_t f2bf(float f) {
    union { float f; unsigned int i; } v;
    v.f = f;
    unsigned int r = v.i + 0x7fffu + ((v.i >> 16) & 1u);  // RNE
    return (ushort_t)(r >> 16);
}

__device__ __forceinline__ void glds16(const ushort_t* g, ushort_t* l) {
    __builtin_amdgcn_global_load_lds(
        (const __attribute__((address_space(1))) void*)g,
        (__attribute__((address_space(3))) void*)l, 16, 0, 0);
}

// --------------------------- pre-pass kernels ------------------------------
__global__ __launch_bounds__(256) void cvt_bf16(const float* __restrict__ src,
                                                ushort_t* __restrict__ dst) {
    const int i = blockIdx.x * 256 + threadIdx.x;
    float4 v = ((const float4*)src)[i];
    ushort4 o;
    o.x = f2bf(v.x); o.y = f2bf(v.y); o.z = f2bf(v.z); o.w = f2bf(v.w);
    ((ushort4*)dst)[i] = o;
}

// W (K x N fp32) -> WT (N x K bf16)
__global__ __launch_bounds__(256) void transpose_cvt(
    const float* __restrict__ W, ushort_t* __restrict__ WT, int K, int N) {
    __shared__ float t[32][33];
    const int tx = threadIdx.x & 31, ty = threadIdx.x >> 5;
    const int n0 = blockIdx.x * 32, k0 = blockIdx.y * 32;
#pragma unroll
    for (int i = 0; i < 4; ++i)
        t[ty + 8 * i][tx] = W[(size_t)(k0 + ty + 8 * i) * N + n0 + tx];
    __syncthreads();
#pragma unroll
    for (int i = 0; i < 4; ++i)
        WT[(size_t)(n0 + ty + 8 * i) * K + k0 + tx] = f2bf(t[tx][ty + 8 * i]);
}

// ------------------------------ MFMA GEMM ----------------------------------
// C = A(M x K bf16 rm) @ BT(N x K bf16 rm)^T. 512 thr = 8 waves (2M x 4N),
// tile 128x512, per-wave 64x128. BK=32, 3-slot LDS ring, 2 phases/K-step.
// MODE 0: bf16 g-chunk out, tanh(gate0)/sigmoid(gates1,2). MODE 1: fp32 FC.
template <int MODE, int K>
__global__ __launch_bounds__(512, 2) void gemm256(
    const ushort_t* __restrict__ A, const ushort_t* __restrict__ BT,
    const float* __restrict__ bias, void* __restrict__ out,
    int c0, int CW) {
    constexpr int NT = K / 32;
    __shared__ ushort_t As[3 * 4096];   // 3 slots x (128 rows x 32 k) = 24 KiB
    __shared__ ushort_t Bs[3 * 16384];  // 3 slots x (512 rows x 32 k) = 96 KiB

    const int tid = threadIdx.x;
    const int lane = tid & 63;
    const int w = tid >> 6;
    const int wr = w >> 2, wc = w & 3;

    // T1: XCD-chunked bijective remap (nwg % 8 == 0 always), M-major within.
    const int gx = gridDim.x;
    const int nwg = gx * gridDim.y;
    int flat = blockIdx.y * gx + blockIdx.x;
    flat = (flat & 7) * (nwg >> 3) + (flat >> 3);
    const int by = flat / gx;
    const int bx = flat - by * gx;
    const int m0 = by * 128;

    int nW, nOut, outstride, gate = 0;
    if (MODE == 0) {
        const int per = CW >> 9;
        gate = bx / per;
        const int nloc = (bx - gate * per) * 512;
        nW = gate * QH + c0 + nloc;
        nOut = gate * CW + nloc;
        outstride = 3 * CW;
    } else {
        nW = bx * 512;
        nOut = nW;
        outstride = QOUT;
    }

    // Staging: A 512 chunks (1/thr), B 2048 chunks (4/thr) per tile.
    // LDS linear; global source pre-swizzled: gsrc = glds ^ ((row>>1)&3).
    const int ca = w * 64 + lane;
    const int ra = ca >> 2;
    size_t aoffA = (size_t)(m0 + ra) * K + ((ca & 3) ^ ((ra >> 1) & 3)) * 8;
    const int ldsoA = w * 512;  // wave-uniform elems (HW adds lane*16B)
    size_t boffB[4];
    int ldsoB[4];
#pragma unroll
    for (int t = 0; t < 4; ++t) {
        const int c = t * 512 + w * 64 + lane;
        const int r = c >> 2;
        boffB[t] = (size_t)(nW + r) * K + ((c & 3) ^ ((r >> 1) & 3)) * 8;
        ldsoB[t] = t * 4096 + w * 512;
    }

    const int fl = lane & 15, fq = lane >> 4;
    const int laneoff = fl * 32 + ((fq ^ ((fl >> 1) & 3)) << 3);

    f32x4 acc[4][8];
#pragma unroll
    for (int i = 0; i < 4; ++i)
#pragma unroll
        for (int j = 0; j < 8; ++j) acc[i][j] = {0.f, 0.f, 0.f, 0.f};

    // Prologue: stage tiles 0,1 -> slots 0,1; wait tile0 (5 newest in flight).
#pragma unroll
    for (int t = 0; t < 2; ++t) {
        glds16(A + aoffA + t * 32, &As[t * 4096 + ldsoA]);
#pragma unroll
        for (int tt = 0; tt < 4; ++tt)
            glds16(BT + boffB[tt] + t * 32, &Bs[t * 16384 + ldsoB[tt]]);
    }
    asm volatile("s_waitcnt vmcnt(5)" ::: "memory");
    __builtin_amdgcn_s_barrier();

    int cur = 0, stg = 2;
    for (int kt = 0; kt < NT; ++kt) {
        const int sA = cur * 4096 + wr * 2048 + laneoff;
        const int sB = cur * 16384 + wc * 4096 + laneoff;
        const bool pf = (kt + 2 < NT);
        const size_t kb = (size_t)(kt + 2) * 32;

        bf16x8 af[4], bv[4], bw[4];
        // ------------- phase 0: j=0..3; stage A + B0 of kt+2 -------------
#pragma unroll
        for (int i = 0; i < 4; ++i) af[i] = *(const bf16x8*)&As[sA + i * 512];
#pragma unroll
        for (int j = 0; j < 4; ++j) bv[j] = *(const bf16x8*)&Bs[sB + j * 512];
        if (pf) {
            glds16(A + aoffA + kb, &As[stg * 4096 + ldsoA]);
            glds16(BT + boffB[0] + kb, &Bs[stg * 16384 + ldsoB[0]]);
        }
        __builtin_amdgcn_sched_barrier(0);
        __builtin_amdgcn_s_barrier();
        asm volatile("s_waitcnt lgkmcnt(0)" ::: "memory");
        __builtin_amdgcn_sched_barrier(0);
        __builtin_amdgcn_s_setprio(1);
#pragma unroll
        for (int i = 0; i < 4; ++i)
#pragma unroll
            for (int j = 0; j < 4; ++j)
                acc[i][j] = __builtin_amdgcn_mfma_f32_16x16x32_bf16(
                    af[i], bv[j], acc[i][j], 0, 0, 0);
        __builtin_amdgcn_s_setprio(0);
        __builtin_amdgcn_sched_barrier(0);
        __builtin_amdgcn_s_barrier();
        // ------------- phase 1: j=4..7 (af reused); stage B1..B3 ---------
#pragma unroll
        for (int j = 0; j < 4; ++j)
            bw[j] = *(const bf16x8*)&Bs[sB + (4 + j) * 512];
        if (pf) {
#pragma unroll
            for (int tt = 1; tt < 4; ++tt)
                glds16(BT + boffB[tt] + kb, &Bs[stg * 16384 + ldsoB[tt]]);
        }
        __builtin_amdgcn_sched_barrier(0);
        __builtin_amdgcn_s_barrier();
        asm volatile("s_waitcnt lgkmcnt(0)" ::: "memory");
        __builtin_amdgcn_sched_barrier(0);
        __builtin_amdgcn_s_setprio(1);
#pragma unroll
        for (int i = 0; i < 4; ++i)
#pragma unroll
            for (int j = 0; j < 4; ++j)
                acc[i][4 + j] = __builtin_amdgcn_mfma_f32_16x16x32_bf16(
                    af[i], bw[j], acc[i][4 + j], 0, 0, 0);
        __builtin_amdgcn_s_setprio(0);
        // End-of-step: tile kt+1 must be retired; in-flight = tile kt+2 (5).
        if (kt < NT - 2)
            asm volatile("s_waitcnt vmcnt(5)" ::: "memory");
        else if (kt == NT - 2)
            asm volatile("s_waitcnt vmcnt(0)" ::: "memory");
        __builtin_amdgcn_sched_barrier(0);
        if (kt < NT - 1) __builtin_amdgcn_s_barrier();
        cur = (cur == 2) ? 0 : cur + 1;
        stg = (stg == 2) ? 0 : stg + 1;
    }

    // Fast activation constants (wave-uniform): v = a*rcp(1+exp2(k*v)) + d.
    const float ak = (gate == 0) ? 2.8853900817779268f : -1.4426950408889634f;
    const float aa = (gate == 0) ? -2.f : 1.f;
    const float ad = (gate == 0) ? 1.f : 0.f;

    // Epilogue. C/D: col = lane&15, row = (lane>>4)*4 + reg. Row-inner j-loop
    // so the sector-stores of each output line issue back-to-back.
    float bvv[8];
#pragma unroll
    for (int j = 0; j < 8; ++j) bvv[j] = bias[nW + wc * 128 + j * 16 + fl];
#pragma unroll
    for (int i = 0; i < 4; ++i) {
#pragma unroll
        for (int r = 0; r < 4; ++r) {
            const int row = m0 + wr * 64 + i * 16 + fq * 4 + r;
#pragma unroll
            for (int j = 0; j < 8; ++j) {
                const int col = nOut + wc * 128 + j * 16 + fl;
                float v = acc[i][j][r] + bvv[j];
                if (MODE == 0) {
                    v = aa * __builtin_amdgcn_rcpf(
                                 1.f + __builtin_amdgcn_exp2f(ak * v)) +
                        ad;
                    ((ushort_t*)out)[(size_t)row * outstride + col] = f2bf(v);
                } else {
                    ((float*)out)[(size_t)row * outstride + col] = v;
                }
            }
        }
    }
}

// ----------------------- segmented fo-scan (2 passes) ----------------------
// g: (T, B, 3, CW) bf16 activated z,f,o. c = f*c + (1-f)*z as (A,B) pairs.
// 4-wide: each thread owns 4 consecutive hh.

// Pass 1: per-(seg,b,hh4) summary. idx4 covers hh = 4*(idx4 % (CW/4)).
__global__ __launch_bounds__(256) void scan_p1(const ushort_t* __restrict__ g,
                                               float* __restrict__ Aseg,
                                               float* __restrict__ Bseg,
                                               int CW) {
    const int idx4 = blockIdx.x * 256 + threadIdx.x;
    const int cw4 = CW >> 2;
    const int hh = (idx4 % cw4) << 2;
    const int sb = idx4 / cw4;
    const int b = sb % QB;
    const int s = sb / QB;
    const ushort_t* gp = g + ((size_t)(s * SL * QB + b) * 3) * CW + hh;
    const size_t grow = (size_t)QB * 3 * CW;
    uint2 zu[SL], fu[SL];
#pragma unroll
    for (int t = 0; t < SL; ++t) {
        zu[t] = *(const uint2*)gp;
        fu[t] = *(const uint2*)(gp + CW);
        gp += grow;
    }
    float4 A = {1.f, 1.f, 1.f, 1.f}, Bc = {0.f, 0.f, 0.f, 0.f};
#pragma unroll
    for (int t = 0; t < SL; ++t) {
        const float f0 = blo(fu[t].x), f1 = bhi(fu[t].x);
        const float f2 = blo(fu[t].y), f3 = bhi(fu[t].y);
        Bc.x = f0 * Bc.x + (1.f - f0) * blo(zu[t].x);
        Bc.y = f1 * Bc.y + (1.f - f1) * bhi(zu[t].x);
        Bc.z = f2 * Bc.z + (1.f - f2) * blo(zu[t].y);
        Bc.w = f3 * Bc.w + (1.f - f3) * bhi(zu[t].y);
        A.x *= f0; A.y *= f1; A.z *= f2; A.w *= f3;
    }
    const size_t oidx = (size_t)sb * CW + hh;
    *(float4*)&Aseg[oidx] = A;
    *(float4*)&Bseg[oidx] = Bc;
}

// Pass 2 (p2+p3 fused): inline-scan preceding segment summaries for cstart,
// then recompute interior states, write h (bf16, 4-wide).
__global__ __launch_bounds__(256) void scan_p3(const ushort_t* __restrict__ g,
                                               const float* __restrict__ Aseg,
                                               const float* __restrict__ Bseg,
                                               ushort_t* __restrict__ h,
                                               int c0, int CW) {
    const int idx4 = blockIdx.x * 256 + threadIdx.x;
    const int cw4 = CW >> 2;
    const int hh = (idx4 % cw4) << 2;
    const int sb = idx4 / cw4;
    const int b = sb % QB;
    const int s = sb / QB;
    const ushort_t* gp = g + ((size_t)(s * SL * QB + b) * 3) * CW + hh;
    ushort_t* hp = h + (size_t)(s * SL * QB + b) * QH + c0 + hh;
    const size_t grow = (size_t)QB * 3 * CW;
    const size_t hrow = (size_t)QB * QH;
    uint2 zu[SL], fu[SL], ou[SL];
#pragma unroll
    for (int t = 0; t < SL; ++t) {
        zu[t] = *(const uint2*)gp;
        fu[t] = *(const uint2*)(gp + CW);
        ou[t] = *(const uint2*)(gp + 2 * CW);
        gp += grow;
    }
    // Inline p2: c = fold over segments s' < s of (A,B) summaries.
    float4 c = {0.f, 0.f, 0.f, 0.f};
    const size_t stride = (size_t)QB * CW;
    const size_t colo = (size_t)b * CW + hh;
    for (int sp = 0; sp < s; ++sp) {
        const float4 Av = *(const float4*)&Aseg[sp * stride + colo];
        const float4 Bv = *(const float4*)&Bseg[sp * stride + colo];
        c.x = Av.x * c.x + Bv.x;
        c.y = Av.y * c.y + Bv.y;
        c.z = Av.z * c.z + Bv.z;
        c.w = Av.w * c.w + Bv.w;
    }
#pragma unroll
    for (int t = 0; t < SL; ++t) {
        const float f0 = blo(fu[t].x), f1 = bhi(fu[t].x);
        const float f2 = blo(fu[t].y), f3 = bhi(fu[t].y);
        c.x = f0 * c.x + (1.f - f0) * blo(zu[t].x);
        c.y = f1 * c.y + (1.f - f1) * bhi(zu[t].x);
        c.z = f2 * c.z + (1.f - f2) * blo(zu[t].y);
        c.w = f3 * c.w + (1.f - f3) * bhi(zu[t].y);
        ushort4 hv;
        hv.x = f2bf(blo(ou[t].x) * c.x);
        hv.y = f2bf(bhi(ou[t].x) * c.y);
        hv.z = f2bf(blo(ou[t].y) * c.z);
        hv.w = f2bf(bhi(ou[t].y) * c.w);
        *(ushort4*)hp = hv;
        hp += hrow;
    }
}

extern "C" void kernel_launch(void* const* d_in, const int* in_sizes, int n_in,
                              void* d_out, int out_size, void* d_ws,
                              size_t ws_size, hipStream_t stream) {
    const float* x   = (const float*)d_in[0];
    const float* W0  = (const float*)d_in[1];
    const float* b0  = (const float*)d_in[2];
    const float* W1  = (const float*)d_in[3];
    const float* b1  = (const float*)d_in[4];
    const float* Wfc = (const float*)d_in[5];
    const float* bfc = (const float*)d_in[6];
    float* out = (float*)d_out;

    char* p = (char*)d_ws;
    ushort_t* h0   = (ushort_t*)p;  p += (size_t)QM * QH * 2;
    ushort_t* h1   = (ushort_t*)p;  // x_bf aliases h1 (dead before h1 write)
    ushort_t* x_bf = (ushort_t*)p;  p += (size_t)QM * QH * 2;
    ushort_t* W0T  = (ushort_t*)p;  p += (size_t)3 * QH * QIN * 2;
    ushort_t* W1T  = (ushort_t*)p;  p += (size_t)3 * QH * QH * 2;
    ushort_t* WfcT = (ushort_t*)p;  p += (size_t)QOUT * QH * 2;
    const size_t base = (size_t)(p - (char*)d_ws);

    // CW >= 512 (512-wide GEMT N-tiles). R10 ran CW=512 within ws budget.
    int CW = QH;
    while (CW > 512 &&
           base + 3 * (size_t)QB * CW * SEG * 4 + (size_t)QM * 3 * CW * 2 >
               ws_size)
        CW >>= 1;
    const int nch = QH / CW;

    float* Aseg   = (float*)p;  p += (size_t)QB * CW * SEG * 4;
    float* Bseg   = (float*)p;  p += (size_t)QB * CW * SEG * 4;
    p += (size_t)QB * CW * SEG * 4;  // (former cstart, unused)
    ushort_t* g   = (ushort_t*)p;

    dim3 blk(256);
    dim3 blk5(512);

    cvt_bf16<<<dim3(QM * QIN / 1024), blk, 0, stream>>>(x, x_bf);
    transpose_cvt<<<dim3(3 * QH / 32, QIN / 32), blk, 0, stream>>>(
        W0, W0T, QIN, 3 * QH);
    transpose_cvt<<<dim3(3 * QH / 32, QH / 32), blk, 0, stream>>>(
        W1, W1T, QH, 3 * QH);
    transpose_cvt<<<dim3(QOUT / 32, QH / 32), blk, 0, stream>>>(
        Wfc, WfcT, QH, QOUT);

    const dim3 ggrid(3 * (CW >> 9), QM / 128);
    const dim3 p13grid(SEG * QB * CW / 1024);  // 4-wide threads

    for (int ci = 0; ci < nch; ++ci) {
        gemm256<0, QIN><<<ggrid, blk5, 0, stream>>>(x_bf, W0T, b0, g,
                                                    ci * CW, CW);
        scan_p1<<<p13grid, blk, 0, stream>>>(g, Aseg, Bseg, CW);
        scan_p3<<<p13grid, blk, 0, stream>>>(g, Aseg, Bseg, h0, ci * CW, CW);
    }
    for (int ci = 0; ci < nch; ++ci) {
        gemm256<0, QH><<<ggrid, blk5, 0, stream>>>(h0, W1T, b1, g,
                                                   ci * CW, CW);
        scan_p1<<<p13grid, blk, 0, stream>>>(g, Aseg, Bseg, CW);
        scan_p3<<<p13grid, blk, 0, stream>>>(g, Aseg, Bseg, h1, ci * CW, CW);
    }
    gemm256<1, QH><<<dim3(QOUT / 512, QM / 128), blk5, 0, stream>>>(
        h1, WfcT, bfc, out, 0, 0);
}

// Round 9
// 672.081 us; speedup vs baseline: 1.0462x; 1.0462x over previous
//
#include <hip/hip_runtime.h>
#include <hip/hip_bf16.h>

// QRNN: T=512, B=64, IN=512, H=1024, OUT=512. fp32 in/out.
// R12 (3rd resubmit; R6-R8 bench slots lost to GPUAcquisitionTimeout).
// Register-pipelined K-loop. R11 refuted the L3-restream theory (BN
// 256->512 changed nothing); the real limiter is read<->MFMA lockstep:
// MfmaUtil 35.7% == MFMA-cyc/step-time (1081/3025) exactly. Fix: issue each
// phase's fragments ONE PHASE EARLY, wait with counted lgkmcnt(4/8) (not 0)
// so LDS service overlaps the MFMA cluster. A-frag regs reused (reads issue
// after consuming MFMAs in program order); B double-buffered (Bx/By, static
// parity via step-pair). Per-step vmcnt moved BEFORE the mid-step barrier so
// slot kt+1 is cross-wave published before phase-1 issues its reads.
// vmcnt: keep {kt+3-A, kt+2-B, kt+2-A} = 6 (tail 4/0). Geometry as R10:
// 256x256 tile, 8 waves 2Mx4N, wave-tile 128x64, BK=32, 4-slot ring.
// MFMA K-order unchanged -> bitwise-same output.
// Paper-audited ledgers: lgkm phase0 12->4 retires {A0,BC}; phase1 12->8
// retires {A1}; LDS WAR on slot kt-1 gated by end-of-step barrier; vmcnt 6
// newest = {A(kt+3), B(kt+2), A(kt+2)} -> tile kt+1 resident at publish.
// Retained: XCD-chunked bijective remap, 0-conflict XOR swizzle, fast
// exp2/rcp activations, row-inner epilogue, 4-wide scans, p2-in-p3 fold,
// bf16 g, x_bf aliased into h1, CW chunks (min 256), RNE f2bf.

#define QT 512
#define QB 64
#define QIN 512
#define QH 1024
#define QOUT 512
#define QM (QT * QB)
#define SEG 32
#define SL (QT / SEG)  // 16

typedef unsigned short ushort_t;
typedef __attribute__((ext_vector_type(8))) short bf16x8;
typedef __attribute__((ext_vector_type(4))) float f32x4;

__device__ __forceinline__ float blo(unsigned int u) {
    union { unsigned int i; float f; } v;
    v.i = u << 16;
    return v.f;
}

__device__ __forceinline__ float bhi(unsigned int u) {
    union { unsigned int i; float f; } v;
    v.i = u & 0xffff0000u;
    return v.f;
}

__device__ __forceinline__ ushort_t f2bf(float f) {
    union { float f; unsigned int i; } v;
    v.f = f;
    unsigned int r = v.i + 0x7fffu + ((v.i >> 16) & 1u);  // RNE
    return (ushort_t)(r >> 16);
}

__device__ __forceinline__ void glds16(const ushort_t* g, ushort_t* l) {
    __builtin_amdgcn_global_load_lds(
        (const __attribute__((address_space(1))) void*)g,
        (__attribute__((address_space(3))) void*)l, 16, 0, 0);
}

// --------------------------- pre-pass kernels ------------------------------
__global__ __launch_bounds__(256) void cvt_bf16(const float* __restrict__ src,
                                                ushort_t* __restrict__ dst) {
    const int i = blockIdx.x * 256 + threadIdx.x;
    float4 v = ((const float4*)src)[i];
    ushort4 o;
    o.x = f2bf(v.x); o.y = f2bf(v.y); o.z = f2bf(v.z); o.w = f2bf(v.w);
    ((ushort4*)dst)[i] = o;
}

// W (K x N fp32) -> WT (N x K bf16)
__global__ __launch_bounds__(256) void transpose_cvt(
    const float* __restrict__ W, ushort_t* __restrict__ WT, int K, int N) {
    __shared__ float t[32][33];
    const int tx = threadIdx.x & 31, ty = threadIdx.x >> 5;
    const int n0 = blockIdx.x * 32, k0 = blockIdx.y * 32;
#pragma unroll
    for (int i = 0; i < 4; ++i)
        t[ty + 8 * i][tx] = W[(size_t)(k0 + ty + 8 * i) * N + n0 + tx];
    __syncthreads();
#pragma unroll
    for (int i = 0; i < 4; ++i)
        WT[(size_t)(n0 + ty + 8 * i) * K + k0 + tx] = f2bf(t[tx][ty + 8 * i]);
}

// ------------------------------ MFMA GEMM ----------------------------------
// C = A(M x K bf16 rm) @ BT(N x K bf16 rm)^T. 512 thr = 8 waves (2M x 4N),
// tile 256x256, per-wave 128x64. BK=32, 4-slot LDS ring, reg-pipelined reads.
// MODE 0: bf16 g-chunk out, tanh(gate0)/sigmoid(gates1,2). MODE 1: fp32 FC.

// One K-step. Entering invariant: A0 (frags 0-3, slot kt) and BC (slot kt)
// ds_reads are the 8 oldest outstanding lgkm ops (issued one phase earlier).
#define QSTEP(KT, BC, BN)                                                     \
  {                                                                           \
    const int kt = (KT);                                                      \
    const int slot = (kt & 3) * 8192;                                         \
    const int sa = slot + wr * 4096 + laneoff;                                \
    const bool pf = (kt + 3 < NT);                                            \
    const int pslot = ((kt + 3) & 3) * 8192;                                  \
    const size_t kb = (size_t)(kt + 3) * 32;                                  \
    /* ---- phase 0: issue A1 (frags 4-7, slot kt); stage A-pair kt+3 ---- */ \
    _Pragma("unroll") for (int i = 0; i < 4; ++i)                             \
        A1[i] = *(const bf16x8*)&As[sa + (4 + i) * 512];                      \
    if (pf) {                                                                 \
      glds16(A + aoff[0] + kb, &As[pslot + ldso[0]]);                         \
      glds16(A + aoff[1] + kb, &As[pslot + ldso[1]]);                         \
    }                                                                         \
    __builtin_amdgcn_sched_barrier(0);                                        \
    __builtin_amdgcn_s_barrier();                                             \
    asm volatile("s_waitcnt lgkmcnt(4)" ::: "memory");                        \
    __builtin_amdgcn_sched_barrier(0);                                        \
    __builtin_amdgcn_s_setprio(1);                                            \
    _Pragma("unroll") for (int i = 0; i < 4; ++i)                             \
        _Pragma("unroll") for (int j = 0; j < 4; ++j)                         \
            acc[i][j] = __builtin_amdgcn_mfma_f32_16x16x32_bf16(              \
                A0[i], BC[j], acc[i][j], 0, 0, 0);                            \
    __builtin_amdgcn_s_setprio(0);                                            \
    __builtin_amdgcn_sched_barrier(0);                                        \
    if (kt < NT - 3)                                                          \
      asm volatile("s_waitcnt vmcnt(6)" ::: "memory");                        \
    else if (kt == NT - 3)                                                    \
      asm volatile("s_waitcnt vmcnt(4)" ::: "memory");                        \
    else if (kt == NT - 2)                                                    \
      asm volatile("s_waitcnt vmcnt(0)" ::: "memory");                        \
    __builtin_amdgcn_sched_barrier(0);                                        \
    __builtin_amdgcn_s_barrier();  /* slot kt+1 now cross-wave published */   \
    /* ---- phase 1: issue next-step BN+A0 from slot kt+1; stage B-pair -- */ \
    if (kt < NT - 1) {                                                        \
      const int sn = ((kt + 1) & 3) * 8192;                                   \
      const int sa2 = sn + wr * 4096 + laneoff;                               \
      const int sb2 = sn + wc * 2048 + laneoff;                               \
      _Pragma("unroll") for (int j = 0; j < 4; ++j)                           \
          BN[j] = *(const bf16x8*)&Bs[sb2 + j * 512];                         \
      _Pragma("unroll") for (int i = 0; i < 4; ++i)                           \
          A0[i] = *(const bf16x8*)&As[sa2 + i * 512];                         \
    }                                                                         \
    if (pf) {                                                                 \
      glds16(BT + boff[0] + kb, &Bs[pslot + ldso[0]]);                        \
      glds16(BT + boff[1] + kb, &Bs[pslot + ldso[1]]);                        \
    }                                                                         \
    __builtin_amdgcn_sched_barrier(0);                                        \
    __builtin_amdgcn_s_barrier();                                             \
    if (kt < NT - 1)                                                          \
      asm volatile("s_waitcnt lgkmcnt(8)" ::: "memory");                      \
    else                                                                      \
      asm volatile("s_waitcnt lgkmcnt(0)" ::: "memory");                      \
    __builtin_amdgcn_sched_barrier(0);                                        \
    __builtin_amdgcn_s_setprio(1);                                            \
    _Pragma("unroll") for (int i = 0; i < 4; ++i)                             \
        _Pragma("unroll") for (int j = 0; j < 4; ++j)                         \
            acc[4 + i][j] = __builtin_amdgcn_mfma_f32_16x16x32_bf16(          \
                A1[i], BC[j], acc[4 + i][j], 0, 0, 0);                        \
    __builtin_amdgcn_s_setprio(0);                                            \
    __builtin_amdgcn_sched_barrier(0);                                        \
    if (kt < NT - 1) __builtin_amdgcn_s_barrier();                            \
  }

template <int MODE, int K>
__global__ __launch_bounds__(512, 2) void gemm256(
    const ushort_t* __restrict__ A, const ushort_t* __restrict__ BT,
    const float* __restrict__ bias, void* __restrict__ out,
    int c0, int CW) {
    constexpr int NT = K / 32;
    __shared__ ushort_t As[4 * 8192];  // 4 slots x (256 rows x 32 k) = 64 KiB
    __shared__ ushort_t Bs[4 * 8192];  // 64 KiB

    const int tid = threadIdx.x;
    const int lane = tid & 63;
    const int w = tid >> 6;
    const int wr = w >> 2, wc = w & 3;

    // T1: XCD-chunked bijective remap (nwg % 8 == 0 always), M-major within.
    const int gx = gridDim.x;
    const int nwg = gx * gridDim.y;
    int flat = blockIdx.y * gx + blockIdx.x;
    flat = (flat & 7) * (nwg >> 3) + (flat >> 3);
    const int by = flat / gx;
    const int bx = flat - by * gx;
    const int m0 = by * 256;

    int nW, nOut, outstride, gate = 0;
    if (MODE == 0) {
        const int per = CW >> 8;
        gate = bx / per;
        const int nloc = (bx - gate * per) * 256;
        nW = gate * QH + c0 + nloc;
        nOut = gate * CW + nloc;
        outstride = 3 * CW;
    } else {
        nW = bx * 256;
        nOut = nW;
        outstride = QOUT;
    }

    // Staging: 1024 16B-chunks per array per tile; thread covers 2 (A) + 2 (B).
    // LDS linear; global source pre-swizzled: gsrc = glds ^ ((row>>1)&3).
    size_t aoff[2], boff[2];
    int ldso[2];
#pragma unroll
    for (int j = 0; j < 2; ++j) {
        const int c = w * 128 + j * 64 + lane;  // chunk id 0..1023
        const int r = c >> 2;
        const int gs = (c & 3) ^ ((r >> 1) & 3);
        aoff[j] = (size_t)(m0 + r) * K + gs * 8;
        boff[j] = (size_t)(nW + r) * K + gs * 8;
        ldso[j] = w * 1024 + j * 512;  // wave-uniform elems (HW adds lane*16B)
    }

    const int fl = lane & 15, fq = lane >> 4;
    const int laneoff = fl * 32 + ((fq ^ ((fl >> 1) & 3)) << 3);

    f32x4 acc[8][4];
#pragma unroll
    for (int i = 0; i < 8; ++i)
#pragma unroll
        for (int j = 0; j < 4; ++j) acc[i][j] = {0.f, 0.f, 0.f, 0.f};

    // Prologue: stage tiles 0,1,2 -> slots 0,1,2; publish tile0; preload
    // A0/Bx (phase-(0,0) operands) so the loop invariant holds at entry.
#pragma unroll
    for (int t = 0; t < 3; ++t) {
        const int slot = t * 8192;
        glds16(A + aoff[0] + t * 32, &As[slot + ldso[0]]);
        glds16(A + aoff[1] + t * 32, &As[slot + ldso[1]]);
        glds16(BT + boff[0] + t * 32, &Bs[slot + ldso[0]]);
        glds16(BT + boff[1] + t * 32, &Bs[slot + ldso[1]]);
    }
    asm volatile("s_waitcnt vmcnt(8)" ::: "memory");
    __builtin_amdgcn_s_barrier();

    bf16x8 A0[4], A1[4], Bx[4], By[4];
    {
        const int sa0 = wr * 4096 + laneoff;
        const int sb0 = wc * 2048 + laneoff;
#pragma unroll
        for (int i = 0; i < 4; ++i) A0[i] = *(const bf16x8*)&As[sa0 + i * 512];
#pragma unroll
        for (int j = 0; j < 4; ++j) Bx[j] = *(const bf16x8*)&Bs[sb0 + j * 512];
    }

#pragma unroll 1
    for (int k2 = 0; k2 < NT / 2; ++k2) {
        QSTEP(2 * k2, Bx, By)
        QSTEP(2 * k2 + 1, By, Bx)
    }

    // Fast activation constants (wave-uniform): v = a*rcp(1+exp2(k*v)) + d.
    const float ak = (gate == 0) ? 2.8853900817779268f : -1.4426950408889634f;
    const float aa = (gate == 0) ? -2.f : 1.f;
    const float ad = (gate == 0) ? 1.f : 0.f;

    // Epilogue. C/D: col = lane&15, row = (lane>>4)*4 + reg. Row-inner j-loop
    // so the 4 32B sector-stores of each 128B line issue back-to-back.
    float bvv[4];
#pragma unroll
    for (int j = 0; j < 4; ++j) bvv[j] = bias[nW + wc * 64 + j * 16 + fl];
#pragma unroll
    for (int i = 0; i < 8; ++i) {
#pragma unroll
        for (int r = 0; r < 4; ++r) {
            const int row = m0 + wr * 128 + i * 16 + fq * 4 + r;
#pragma unroll
            for (int j = 0; j < 4; ++j) {
                const int col = nOut + wc * 64 + j * 16 + fl;
                float v = acc[i][j][r] + bvv[j];
                if (MODE == 0) {
                    v = aa * __builtin_amdgcn_rcpf(
                                 1.f + __builtin_amdgcn_exp2f(ak * v)) +
                        ad;
                    ((ushort_t*)out)[(size_t)row * outstride + col] = f2bf(v);
                } else {
                    ((float*)out)[(size_t)row * outstride + col] = v;
                }
            }
        }
    }
}

// ----------------------- segmented fo-scan (2 passes) ----------------------
// g: (T, B, 3, CW) bf16 activated z,f,o. c = f*c + (1-f)*z as (A,B) pairs.
// 4-wide: each thread owns 4 consecutive hh.

// Pass 1: per-(seg,b,hh4) summary. idx4 covers hh = 4*(idx4 % (CW/4)).
__global__ __launch_bounds__(256) void scan_p1(const ushort_t* __restrict__ g,
                                               float* __restrict__ Aseg,
                                               float* __restrict__ Bseg,
                                               int CW) {
    const int idx4 = blockIdx.x * 256 + threadIdx.x;
    const int cw4 = CW >> 2;
    const int hh = (idx4 % cw4) << 2;
    const int sb = idx4 / cw4;
    const int b = sb % QB;
    const int s = sb / QB;
    const ushort_t* gp = g + ((size_t)(s * SL * QB + b) * 3) * CW + hh;
    const size_t grow = (size_t)QB * 3 * CW;
    uint2 zu[SL], fu[SL];
#pragma unroll
    for (int t = 0; t < SL; ++t) {
        zu[t] = *(const uint2*)gp;
        fu[t] = *(const uint2*)(gp + CW);
        gp += grow;
    }
    float4 A = {1.f, 1.f, 1.f, 1.f}, Bc = {0.f, 0.f, 0.f, 0.f};
#pragma unroll
    for (int t = 0; t < SL; ++t) {
        const float f0 = blo(fu[t].x), f1 = bhi(fu[t].x);
        const float f2 = blo(fu[t].y), f3 = bhi(fu[t].y);
        Bc.x = f0 * Bc.x + (1.f - f0) * blo(zu[t].x);
        Bc.y = f1 * Bc.y + (1.f - f1) * bhi(zu[t].x);
        Bc.z = f2 * Bc.z + (1.f - f2) * blo(zu[t].y);
        Bc.w = f3 * Bc.w + (1.f - f3) * bhi(zu[t].y);
        A.x *= f0; A.y *= f1; A.z *= f2; A.w *= f3;
    }
    const size_t oidx = (size_t)sb * CW + hh;
    *(float4*)&Aseg[oidx] = A;
    *(float4*)&Bseg[oidx] = Bc;
}

// Pass 2 (p2+p3 fused): inline-scan preceding segment summaries for cstart,
// then recompute interior states, write h (bf16, 4-wide).
__global__ __launch_bounds__(256) void scan_p3(const ushort_t* __restrict__ g,
                                               const float* __restrict__ Aseg,
                                               const float* __restrict__ Bseg,
                                               ushort_t* __restrict__ h,
                                               int c0, int CW) {
    const int idx4 = blockIdx.x * 256 + threadIdx.x;
    const int cw4 = CW >> 2;
    const int hh = (idx4 % cw4) << 2;
    const int sb = idx4 / cw4;
    const int b = sb % QB;
    const int s = sb / QB;
    const ushort_t* gp = g + ((size_t)(s * SL * QB + b) * 3) * CW + hh;
    ushort_t* hp = h + (size_t)(s * SL * QB + b) * QH + c0 + hh;
    const size_t grow = (size_t)QB * 3 * CW;
    const size_t hrow = (size_t)QB * QH;
    uint2 zu[SL], fu[SL], ou[SL];
#pragma unroll
    for (int t = 0; t < SL; ++t) {
        zu[t] = *(const uint2*)gp;
        fu[t] = *(const uint2*)(gp + CW);
        ou[t] = *(const uint2*)(gp + 2 * CW);
        gp += grow;
    }
    // Inline p2: c = fold over segments s' < s of (A,B) summaries.
    float4 c = {0.f, 0.f, 0.f, 0.f};
    const size_t stride = (size_t)QB * CW;
    const size_t colo = (size_t)b * CW + hh;
    for (int sp = 0; sp < s; ++sp) {
        const float4 Av = *(const float4*)&Aseg[sp * stride + colo];
        const float4 Bv = *(const float4*)&Bseg[sp * stride + colo];
        c.x = Av.x * c.x + Bv.x;
        c.y = Av.y * c.y + Bv.y;
        c.z = Av.z * c.z + Bv.z;
        c.w = Av.w * c.w + Bv.w;
    }
#pragma unroll
    for (int t = 0; t < SL; ++t) {
        const float f0 = blo(fu[t].x), f1 = bhi(fu[t].x);
        const float f2 = blo(fu[t].y), f3 = bhi(fu[t].y);
        c.x = f0 * c.x + (1.f - f0) * blo(zu[t].x);
        c.y = f1 * c.y + (1.f - f1) * bhi(zu[t].x);
        c.z = f2 * c.z + (1.f - f2) * blo(zu[t].y);
        c.w = f3 * c.w + (1.f - f3) * bhi(zu[t].y);
        ushort4 hv;
        hv.x = f2bf(blo(ou[t].x) * c.x);
        hv.y = f2bf(bhi(ou[t].x) * c.y);
        hv.z = f2bf(blo(ou[t].y) * c.z);
        hv.w = f2bf(bhi(ou[t].y) * c.w);
        *(ushort4*)hp = hv;
        hp += hrow;
    }
}

extern "C" void kernel_launch(void* const* d_in, const int* in_sizes, int n_in,
                              void* d_out, int out_size, void* d_ws,
                              size_t ws_size, hipStream_t stream) {
    const float* x   = (const float*)d_in[0];
    const float* W0  = (const float*)d_in[1];
    const float* b0  = (const float*)d_in[2];
    const float* W1  = (const float*)d_in[3];
    const float* b1  = (const float*)d_in[4];
    const float* Wfc = (const float*)d_in[5];
    const float* bfc = (const float*)d_in[6];
    float* out = (float*)d_out;

    char* p = (char*)d_ws;
    ushort_t* h0   = (ushort_t*)p;  p += (size_t)QM * QH * 2;
    ushort_t* h1   = (ushort_t*)p;  // x_bf aliases h1 (dead before h1 write)
    ushort_t* x_bf = (ushort_t*)p;  p += (size_t)QM * QH * 2;
    ushort_t* W0T  = (ushort_t*)p;  p += (size_t)3 * QH * QIN * 2;
    ushort_t* W1T  = (ushort_t*)p;  p += (size_t)3 * QH * QH * 2;
    ushort_t* WfcT = (ushort_t*)p;  p += (size_t)QOUT * QH * 2;
    const size_t base = (size_t)(p - (char*)d_ws);

    // Largest CW (>=256: 256-wide GEMM tiles) fitting ws.
    int CW = QH;
    while (CW > 256 &&
           base + 3 * (size_t)QB * CW * SEG * 4 + (size_t)QM * 3 * CW * 2 >
               ws_size)
        CW >>= 1;
    const int nch = QH / CW;

    float* Aseg   = (float*)p;  p += (size_t)QB * CW * SEG * 4;
    float* Bseg   = (float*)p;  p += (size_t)QB * CW * SEG * 4;
    p += (size_t)QB * CW * SEG * 4;  // (former cstart, unused)
    ushort_t* g   = (ushort_t*)p;

    dim3 blk(256);
    dim3 blk5(512);

    cvt_bf16<<<dim3(QM * QIN / 1024), blk, 0, stream>>>(x, x_bf);
    transpose_cvt<<<dim3(3 * QH / 32, QIN / 32), blk, 0, stream>>>(
        W0, W0T, QIN, 3 * QH);
    transpose_cvt<<<dim3(3 * QH / 32, QH / 32), blk, 0, stream>>>(
        W1, W1T, QH, 3 * QH);
    transpose_cvt<<<dim3(QOUT / 32, QH / 32), blk, 0, stream>>>(
        Wfc, WfcT, QH, QOUT);

    const dim3 ggrid(3 * (CW >> 8), QM / 256);
    const dim3 p13grid(SEG * QB * CW / 1024);  // 4-wide threads

    for (int ci = 0; ci < nch; ++ci) {
        gemm256<0, QIN><<<ggrid, blk5, 0, stream>>>(x_bf, W0T, b0, g,
                                                    ci * CW, CW);
        scan_p1<<<p13grid, blk, 0, stream>>>(g, Aseg, Bseg, CW);
        scan_p3<<<p13grid, blk, 0, stream>>>(g, Aseg, Bseg, h0, ci * CW, CW);
    }
    for (int ci = 0; ci < nch; ++ci) {
        gemm256<0, QH><<<ggrid, blk5, 0, stream>>>(h0, W1T, b1, g,
                                                   ci * CW, CW);
        scan_p1<<<p13grid, blk, 0, stream>>>(g, Aseg, Bseg, CW);
        scan_p3<<<p13grid, blk, 0, stream>>>(g, Aseg, Bseg, h1, ci * CW, CW);
    }
    gemm256<1, QH><<<dim3(QOUT / 256, QM / 256), blk5, 0, stream>>>(
        h1, WfcT, bfc, out, 0, 0);
}